// Round 4
// baseline (218.736 us; speedup 1.0000x reference)
//
#include <hip/hip_runtime.h>
#include <stdint.h>

// ---- problem constants ----
#define Bz 8
#define Tz 1024
#define Cz 768
#define Hz 8
#define Dz 96
#define BHz 64            // Bz*Hz
#define Kz 768

typedef __bf16 bf16x8 __attribute__((ext_vector_type(8)));
typedef unsigned short u16x8 __attribute__((ext_vector_type(8)));
typedef float f32x4 __attribute__((ext_vector_type(4)));

__device__ __forceinline__ unsigned short f2bf(float f) {
  union { float f; unsigned int u; } v; v.f = f;
  unsigned int u = v.u;
  return (unsigned short)((u + 0x7fffu + ((u >> 16) & 1u)) >> 16);
}

#if defined(__has_builtin)
#if __has_builtin(__builtin_amdgcn_exp2f)
#define EXP2(x) __builtin_amdgcn_exp2f(x)
#endif
#endif
#ifndef EXP2
#define EXP2(x) __expf((x) * 0.6931471805599453f)
#endif

// async global->LDS, 16B per lane; LDS dest must be wave-uniform base (+lane*16 implicit)
typedef const __attribute__((address_space(1))) void* gas_ptr;
typedef __attribute__((address_space(3))) void* las_ptr;
__device__ __forceinline__ void gl16(const void* g, void* l) {
  __builtin_amdgcn_global_load_lds((gas_ptr)g, (las_ptr)l, 16, 0, 0);
}

// ---- cast x (fp32) -> bf16, 4 elems/thread ----
__global__ __launch_bounds__(256) void cast_f32_bf16(const float* __restrict__ in,
                                                     unsigned short* __restrict__ out) {
  int i = (blockIdx.x * 256 + threadIdx.x) * 4;
  float4 v = *(const float4*)(in + i);
  union { unsigned short s[4]; uint2 u; } o;
  o.s[0] = f2bf(v.x); o.s[1] = f2bf(v.y); o.s[2] = f2bf(v.z); o.s[3] = f2bf(v.w);
  *(uint2*)(out + i) = o.u;
}

// ---- transpose + cast: in[R][Cc] fp32 -> out[Cc][R] bf16 ----
__global__ __launch_bounds__(256) void transpose_cast(const float* __restrict__ in,
                                                      unsigned short* __restrict__ out,
                                                      int R, int Cc) {
  __shared__ unsigned short t[64][72];
  int bx = blockIdx.x * 64;   // col base of in
  int by = blockIdx.y * 64;   // row base of in
  int tid = threadIdx.x;
#pragma unroll
  for (int i = 0; i < 16; i++) {
    int idx = tid + i * 256;
    int r = idx >> 6, c = idx & 63;
    t[c][r] = f2bf(in[(by + r) * Cc + bx + c]);
  }
  __syncthreads();
#pragma unroll
  for (int i = 0; i < 16; i++) {
    int idx = tid + i * 256;
    int r = idx >> 6, c = idx & 63;
    out[(bx + r) * R + by + c] = t[r][c];
  }
}

// ---- 128x128 MFMA bf16 GEMM with global_load_lds staging (m97 structure) ----
// XCD-aware bijective block swizzle (nwg % 8 == 0 for both launches): each XCD
// gets a contiguous bm-major run -> B-panels L2-resident per XCD.
// MODE 0: epilogue scatters bf16 into qkv: Q,K as [which][64][1024][96];
//         V third written TRANSPOSED as [64][96][1024] (V^T).
// MODE 1: epilogue writes fp32 C[M][768]
template <int MODE>
__global__ __launch_bounds__(256)
void gemm128(const unsigned short* __restrict__ A,
             const unsigned short* __restrict__ Bt,
             unsigned short* __restrict__ obf,
             float* __restrict__ of32) {
  __shared__ unsigned short Asm[128 * 32];  // unpadded: required by global_load_lds lane order
  __shared__ unsigned short Bsm[128 * 32];
  const int tid = threadIdx.x;
  const int wave = tid >> 6, lane = tid & 63;
  const int quad = lane >> 4, l16 = lane & 15;
  // XCD swizzle: lin -> (lin%8)*cpx + lin/8, decoded bm-major (gridDim.x == 64)
  const int lin = blockIdx.x + (blockIdx.y << 6);
  const int cpx = (gridDim.x * gridDim.y) >> 3;
  const int nl = (lin & 7) * cpx + (lin >> 3);
  const int bm = nl & 63, bn = nl >> 6;
  const int wm = (wave >> 1) * 64, wn = (wave & 1) * 64;

  f32x4 zero = {0.f, 0.f, 0.f, 0.f};
  f32x4 acc[4][4];
#pragma unroll
  for (int i = 0; i < 4; i++)
#pragma unroll
    for (int j = 0; j < 4; j++) acc[i][j] = zero;

  // staging map: wave w issue q covers rows w*32+q*16 .. +15; lane l -> row +(l>>2), k-part (l&3)*8
  const int rr = lane >> 2, c8 = (lane & 3) * 8;
  const unsigned short* Ag0 = A + (size_t)(bm * 128 + wave * 32 + rr) * Kz + c8;
  const unsigned short* Ag1 = Ag0 + 16 * Kz;
  const unsigned short* Bg0 = Bt + (size_t)(bn * 128 + wave * 32 + rr) * Kz + c8;
  const unsigned short* Bg1 = Bg0 + 16 * Kz;
  unsigned short* lA0 = &Asm[wave * 1024];      // elements; bytes = wave*2048
  unsigned short* lA1 = lA0 + 512;
  unsigned short* lB0 = &Bsm[wave * 1024];
  unsigned short* lB1 = lB0 + 512;

  for (int k0 = 0; k0 < Kz; k0 += 32) {
    __syncthreads();                 // WAR: previous frag reads done
    gl16(Ag0 + k0, lA0);
    gl16(Ag1 + k0, lA1);
    gl16(Bg0 + k0, lB0);
    gl16(Bg1 + k0, lB1);
    __syncthreads();                 // drains vmcnt(0) then barrier
    bf16x8 af[4], bfr[4];
#pragma unroll
    for (int mi = 0; mi < 4; mi++)
      af[mi] = *(const bf16x8*)&Asm[(wm + mi * 16 + l16) * 32 + quad * 8];
#pragma unroll
    for (int ni = 0; ni < 4; ni++)
      bfr[ni] = *(const bf16x8*)&Bsm[(wn + ni * 16 + l16) * 32 + quad * 8];
#pragma unroll
    for (int mi = 0; mi < 4; mi++)
#pragma unroll
      for (int ni = 0; ni < 4; ni++)
        acc[mi][ni] = __builtin_amdgcn_mfma_f32_16x16x32_bf16(af[mi], bfr[ni], acc[mi][ni], 0, 0, 0);
  }

#pragma unroll
  for (int mi = 0; mi < 4; mi++) {
    int row = bm * 128 + wm + mi * 16 + quad * 4;
    if (MODE == 0) {
      int b = row >> 10;
      int t = row & 1023;
#pragma unroll
      for (int ni = 0; ni < 4; ni++) {
        int col = bn * 128 + wn + ni * 16 + l16;
        int which = col / 768;        // wave-uniform per fragment (16 | 768)
        int cc = col - which * 768;
        int h = cc / 96;
        int d = cc - h * 96;
        if (which == 2) {
          // V^T layout: [bh][d][t]; r increments t -> 4 contiguous bf16 = one 8B store
          int base = ((2 * 64 + b * 8 + h) * 96 + d) * 1024 + t;
          union { unsigned short s[4]; uint2 u; } o;
#pragma unroll
          for (int r = 0; r < 4; r++) o.s[r] = f2bf(acc[mi][ni][r]);
          *(uint2*)(obf + base) = o.u;
        } else {
          int base = ((which * 64 + b * 8 + h) * 1024 + t) * 96 + d;
#pragma unroll
          for (int r = 0; r < 4; r++) obf[base + r * 96] = f2bf(acc[mi][ni][r]);
        }
      }
    } else {
#pragma unroll
      for (int ni = 0; ni < 4; ni++) {
        int col = bn * 128 + wn + ni * 16 + l16;
#pragma unroll
        for (int r = 0; r < 4; r++) of32[(row + r) * 768 + col] = acc[mi][ni][r];
      }
    }
  }
}

// ---- flash attention: 1 block = (b,h) x 64 q-rows; 4 waves x 16 rows; BS=128 ----
// Round 4: smaller blocks to raise wave supply — grid 64x16 = 1024 blocks,
// LDS 43.5KB -> 3 blocks/CU (12 waves/CU vs 8). Tile j = 15-by gives descending
// sizes; CU classes (g mod 4) get balanced {8,6,4,2}/{7,5,3,1} iteration sets.
__global__ __launch_bounds__(256, 3)
void attn(const unsigned short* __restrict__ qkv, unsigned short* __restrict__ y) {
  const int bh = blockIdx.x;
  const int by = blockIdx.y;
  const int q0 = (15 - by) * 64;           // heavy tiles dispatch first, class-balanced
  const int tid = threadIdx.x;
  const int wave = tid >> 6, lane = tid & 63;
  const int quad = lane >> 4, l16 = lane & 15;
  const int qw0 = q0 + wave * 16;          // this wave's 16 q-rows (1 m-tile)
  const int b = bh >> 3, h = bh & 7;

  const unsigned short* Qh = qkv + bh * Tz * Dz;
  const unsigned short* Kh = qkv + (BHz + bh) * Tz * Dz;
  const unsigned short* Vt = qkv + 2 * BHz * Tz * Dz + bh * Dz * Tz;  // V^T [d][t]

  __shared__ unsigned short Vsm[96 * 136];       // V^T [d][s], stride 136 (26112 B)
  __shared__ unsigned short Psm[4 * 16 * 136];   // per-wave P [16 q][128 s] (17408 B)
  unsigned short* Pw = Psm + wave * 16 * 136;

  // V staging thread map: round g covers rows g*16 + (tid>>4), 16B chunk tid&15
  const int vd = tid >> 4;
  const int vc = tid & 15;

  bf16x8 aq[3];
#pragma unroll
  for (int kd = 0; kd < 3; kd++)
    aq[kd] = *(const bf16x8*)(Qh + (qw0 + l16) * Dz + kd * 32 + quad * 8);

  f32x4 zero = {0.f, 0.f, 0.f, 0.f};
  f32x4 acc_o[6];
#pragma unroll
  for (int i = 0; i < 6; i++) acc_o[i] = zero;
  const float NEG = -__builtin_inff();
  float mrow[4], lrow[4];                  // mrow raw-score domain; lrow per-LANE partial
#pragma unroll
  for (int r = 0; r < 4; r++) { mrow[r] = NEG; lrow[r] = 0.f; }
  const float cs = 0.14724538519872735f;   // (1/sqrt(96)) * log2(e): exp2-domain softmax

  const int s_last = (q0 >> 7) << 7;       // floor(q0/128)*128
  for (int s0 = 0; s0 <= s_last; s0 += 128) {
    // ---- T14 issue-early: V^T tile global->reg; latency hides under QK^T+softmax ----
    u16x8 vreg[6];
#pragma unroll
    for (int g = 0; g < 6; g++)
      vreg[g] = *(const u16x8*)(Vt + (g * 16 + vd) * Tz + s0 + vc * 8);

    const int srem = qw0 + 15 - s0;              // >= 15 always; srem%16==15
    const int nlim = min(7, srem >> 4);          // last 16-wide s tile with unmasked cols
    const int klim = min(3, srem >> 5);          // last 32-wide PV k chunk

    // ---- S = Q K^T ----
    f32x4 sacc[8];
#pragma unroll
    for (int ni = 0; ni < 8; ni++) {
      if (ni <= nlim) {
        sacc[ni] = zero;
#pragma unroll
        for (int kd = 0; kd < 3; kd++) {
          bf16x8 bk = *(const bf16x8*)(Kh + (s0 + ni * 16 + l16) * Dz + kd * 32 + quad * 8);
          sacc[ni] = __builtin_amdgcn_mfma_f32_16x16x32_bf16(aq[kd], bk, sacc[ni], 0, 0, 0);
        }
      }
    }

    // ---- online softmax; P written to this wave's LDS region ----
    float rmax[4] = {NEG, NEG, NEG, NEG};
#pragma unroll
    for (int ni = 0; ni < 8; ni++) {
      if (ni <= nlim) {
        // mask only tiles that straddle/cross the diagonal (wave-uniform test)
        if (s0 + ni * 16 + 15 > qw0) {
          const int t_base = qw0 + quad * 4;
          const int s_abs = s0 + ni * 16 + l16;
#pragma unroll
          for (int r = 0; r < 4; r++)
            if (s_abs > t_base + r) sacc[ni][r] = NEG;
        }
#pragma unroll
        for (int r = 0; r < 4; r++) rmax[r] = fmaxf(rmax[r], sacc[ni][r]);
      }
    }
#pragma unroll
    for (int r = 0; r < 4; r++)
#pragma unroll
      for (int sh = 1; sh < 16; sh <<= 1)
        rmax[r] = fmaxf(rmax[r], __shfl_xor(rmax[r], sh));

    // deferred rescale (T13): only pay the alpha pass when max grew past threshold
    // 54 raw ~= 8 exp2-units -> p bounded by 2^8, fine in bf16/f32
    int ok = 1;
#pragma unroll
    for (int r = 0; r < 4; r++) ok &= (rmax[r] <= mrow[r] + 54.0f) ? 1 : 0;
    if (!__all(ok)) {
#pragma unroll
      for (int r = 0; r < 4; r++) {
        float mnew = fmaxf(mrow[r], rmax[r]);
        float alpha = EXP2((mrow[r] - mnew) * cs);   // m=-inf -> alpha=0 first iter
        mrow[r] = mnew;
        lrow[r] *= alpha;
#pragma unroll
        for (int di = 0; di < 6; di++) acc_o[di][r] *= alpha;
      }
    }

    float nmc[4];
#pragma unroll
    for (int r = 0; r < 4; r++) nmc[r] = -mrow[r] * cs;
    float rsum[4] = {0.f, 0.f, 0.f, 0.f};
#pragma unroll
    for (int ni = 0; ni < 8; ni++) {
      if (ni <= nlim) {
#pragma unroll
        for (int r = 0; r < 4; r++) {
          float p = EXP2(fmaf(sacc[ni][r], cs, nmc[r]));  // masked: exp2(-inf)=0
          rsum[r] += p;
          Pw[(quad * 4 + r) * 136 + ni * 16 + l16] = f2bf(p);
        }
      }
    }
#pragma unroll
    for (int r = 0; r < 4; r++) lrow[r] += rsum[r];   // per-lane partial; reduce at end

    // zero-fill: when nlim is even, PV chunk klim reads unwritten tile nlim+1
    if (nlim < 7 && !(nlim & 1)) {
      const int zc = (nlim + 1) * 16 + l16;
#pragma unroll
      for (int r = 0; r < 4; r++) Pw[(quad * 4 + r) * 136 + zc] = 0;
    }

    // ---- T14 write-late: V regs -> LDS after WAR barrier (vectorized b128) ----
    __syncthreads();                 // prior iter's Vsm reads done
#pragma unroll
    for (int g = 0; g < 6; g++)
      *(u16x8*)&Vsm[(g * 16 + vd) * 136 + vc * 8] = vreg[g];
    __syncthreads();                 // Vsm ready

    // ---- O += P V : P from own-wave LDS (lgkmcnt orders), V from Vsm ----
#pragma unroll
    for (int kc = 0; kc < 4; kc++) {
      if (kc <= klim) {
        bf16x8 ap = *(const bf16x8*)&Pw[l16 * 136 + kc * 32 + quad * 8];
#pragma unroll
        for (int di = 0; di < 6; di++) {
          bf16x8 bv = *(const bf16x8*)&Vsm[(di * 16 + l16) * 136 + kc * 32 + quad * 8];
          acc_o[di] = __builtin_amdgcn_mfma_f32_16x16x32_bf16(ap, bv, acc_o[di], 0, 0, 0);
        }
      }
    }
  }

#pragma unroll
  for (int r = 0; r < 4; r++) {
#pragma unroll
    for (int sh = 1; sh < 16; sh <<= 1)
      lrow[r] += __shfl_xor(lrow[r], sh);          // deferred l reduction
    float linv = 1.f / lrow[r];
    int t = qw0 + quad * 4 + r;
#pragma unroll
    for (int di = 0; di < 6; di++) {
      int d = di * 16 + l16;
      y[(b * Tz + t) * Cz + h * Dz + d] = f2bf(acc_o[di][r] * linv);
    }
  }
}

// ---- workspace layout (bytes) ----
#define OFF_XB   0u
#define OFF_WAT  12582912u            // 8192*768*2
#define OFF_WPT  16121856u            // + 2304*768*2
#define OFF_QKV  17301504u            // + 768*768*2
#define OFF_Y    55050240u            // + 3*64*1024*96*2

extern "C" void kernel_launch(void* const* d_in, const int* in_sizes, int n_in,
                              void* d_out, int out_size, void* d_ws, size_t ws_size,
                              hipStream_t stream) {
  const float* x  = (const float*)d_in[0];
  const float* Wa = (const float*)d_in[1];
  const float* Wp = (const float*)d_in[2];
  float* out = (float*)d_out;
  uint8_t* ws = (uint8_t*)d_ws;
  unsigned short* xb  = (unsigned short*)(ws + OFF_XB);
  unsigned short* Wat = (unsigned short*)(ws + OFF_WAT);
  unsigned short* Wpt = (unsigned short*)(ws + OFF_WPT);
  unsigned short* qkv = (unsigned short*)(ws + OFF_QKV);
  unsigned short* y   = (unsigned short*)(ws + OFF_Y);

  cast_f32_bf16<<<6144, 256, 0, stream>>>(x, xb);
  transpose_cast<<<dim3(36, 12), 256, 0, stream>>>(Wa, Wat, 768, 2304);
  transpose_cast<<<dim3(12, 12), 256, 0, stream>>>(Wp, Wpt, 768, 768);
  gemm128<0><<<dim3(64, 18), 256, 0, stream>>>(xb, Wat, qkv, nullptr);
  attn<<<dim3(64, 16), 256, 0, stream>>>(qkv, y);
  gemm128<1><<<dim3(64, 6), 256, 0, stream>>>(y, Wpt, nullptr, out);
}

// Round 5
// 206.299 us; speedup vs baseline: 1.0603x; 1.0603x over previous
//
#include <hip/hip_runtime.h>
#include <stdint.h>

// ---- problem constants ----
#define Bz 8
#define Tz 1024
#define Cz 768
#define Hz 8
#define Dz 96
#define BHz 64            // Bz*Hz
#define Kz 768

typedef __bf16 bf16x8 __attribute__((ext_vector_type(8)));
typedef unsigned short u16x8 __attribute__((ext_vector_type(8)));
typedef float f32x4 __attribute__((ext_vector_type(4)));

__device__ __forceinline__ unsigned short f2bf(float f) {
  union { float f; unsigned int u; } v; v.f = f;
  unsigned int u = v.u;
  return (unsigned short)((u + 0x7fffu + ((u >> 16) & 1u)) >> 16);
}

#if defined(__has_builtin)
#if __has_builtin(__builtin_amdgcn_exp2f)
#define EXP2(x) __builtin_amdgcn_exp2f(x)
#endif
#endif
#ifndef EXP2
#define EXP2(x) __expf((x) * 0.6931471805599453f)
#endif

// async global->LDS, 16B per lane; LDS dest must be wave-uniform base (+lane*16 implicit)
typedef const __attribute__((address_space(1))) void* gas_ptr;
typedef __attribute__((address_space(3))) void* las_ptr;
__device__ __forceinline__ void gl16(const void* g, void* l) {
  __builtin_amdgcn_global_load_lds((gas_ptr)g, (las_ptr)l, 16, 0, 0);
}

// ---- cast x (fp32) -> bf16, 4 elems/thread ----
__global__ __launch_bounds__(256) void cast_f32_bf16(const float* __restrict__ in,
                                                     unsigned short* __restrict__ out) {
  int i = (blockIdx.x * 256 + threadIdx.x) * 4;
  float4 v = *(const float4*)(in + i);
  union { unsigned short s[4]; uint2 u; } o;
  o.s[0] = f2bf(v.x); o.s[1] = f2bf(v.y); o.s[2] = f2bf(v.z); o.s[3] = f2bf(v.w);
  *(uint2*)(out + i) = o.u;
}

// ---- transpose + cast: in[R][Cc] fp32 -> out[Cc][R] bf16 ----
__global__ __launch_bounds__(256) void transpose_cast(const float* __restrict__ in,
                                                      unsigned short* __restrict__ out,
                                                      int R, int Cc) {
  __shared__ unsigned short t[64][72];
  int bx = blockIdx.x * 64;   // col base of in
  int by = blockIdx.y * 64;   // row base of in
  int tid = threadIdx.x;
#pragma unroll
  for (int i = 0; i < 16; i++) {
    int idx = tid + i * 256;
    int r = idx >> 6, c = idx & 63;
    t[c][r] = f2bf(in[(by + r) * Cc + bx + c]);
  }
  __syncthreads();
#pragma unroll
  for (int i = 0; i < 16; i++) {
    int idx = tid + i * 256;
    int r = idx >> 6, c = idx & 63;
    out[(bx + r) * R + by + c] = t[r][c];
  }
}

// ---- 128x128 MFMA bf16 GEMM with global_load_lds staging (m97 structure) ----
// Natural block mapping (bm=bx, bn=by): HW round-robin dispatch gives XCD x
// bm in {x, x+8, ...} for every bn -> per-XCD A working set 1.57 MB (L2-resident).
// Round-4 lesson: a contiguous-chunk XCD swizzle DESTROYED this (FETCH 89 MB, +13us).
// MODE 0: epilogue scatters bf16 into qkv: Q,K as [which][64][1024][96];
//         V third written TRANSPOSED as [64][96][1024] (V^T).
// MODE 1: epilogue writes fp32 C[M][768]
template <int MODE>
__global__ __launch_bounds__(256)
void gemm128(const unsigned short* __restrict__ A,
             const unsigned short* __restrict__ Bt,
             unsigned short* __restrict__ obf,
             float* __restrict__ of32) {
  __shared__ unsigned short Asm[128 * 32];  // unpadded: required by global_load_lds lane order
  __shared__ unsigned short Bsm[128 * 32];
  const int tid = threadIdx.x;
  const int wave = tid >> 6, lane = tid & 63;
  const int quad = lane >> 4, l16 = lane & 15;
  const int bm = blockIdx.x, bn = blockIdx.y;
  const int wm = (wave >> 1) * 64, wn = (wave & 1) * 64;

  f32x4 zero = {0.f, 0.f, 0.f, 0.f};
  f32x4 acc[4][4];
#pragma unroll
  for (int i = 0; i < 4; i++)
#pragma unroll
    for (int j = 0; j < 4; j++) acc[i][j] = zero;

  // staging map: wave w issue q covers rows w*32+q*16 .. +15; lane l -> row +(l>>2), k-part (l&3)*8
  const int rr = lane >> 2, c8 = (lane & 3) * 8;
  const unsigned short* Ag0 = A + (size_t)(bm * 128 + wave * 32 + rr) * Kz + c8;
  const unsigned short* Ag1 = Ag0 + 16 * Kz;
  const unsigned short* Bg0 = Bt + (size_t)(bn * 128 + wave * 32 + rr) * Kz + c8;
  const unsigned short* Bg1 = Bg0 + 16 * Kz;
  unsigned short* lA0 = &Asm[wave * 1024];      // elements; bytes = wave*2048
  unsigned short* lA1 = lA0 + 512;
  unsigned short* lB0 = &Bsm[wave * 1024];
  unsigned short* lB1 = lB0 + 512;

  for (int k0 = 0; k0 < Kz; k0 += 32) {
    __syncthreads();                 // WAR: previous frag reads done
    gl16(Ag0 + k0, lA0);
    gl16(Ag1 + k0, lA1);
    gl16(Bg0 + k0, lB0);
    gl16(Bg1 + k0, lB1);
    __syncthreads();                 // drains vmcnt(0) then barrier
    bf16x8 af[4], bfr[4];
#pragma unroll
    for (int mi = 0; mi < 4; mi++)
      af[mi] = *(const bf16x8*)&Asm[(wm + mi * 16 + l16) * 32 + quad * 8];
#pragma unroll
    for (int ni = 0; ni < 4; ni++)
      bfr[ni] = *(const bf16x8*)&Bsm[(wn + ni * 16 + l16) * 32 + quad * 8];
#pragma unroll
    for (int mi = 0; mi < 4; mi++)
#pragma unroll
      for (int ni = 0; ni < 4; ni++)
        acc[mi][ni] = __builtin_amdgcn_mfma_f32_16x16x32_bf16(af[mi], bfr[ni], acc[mi][ni], 0, 0, 0);
  }

#pragma unroll
  for (int mi = 0; mi < 4; mi++) {
    int row = bm * 128 + wm + mi * 16 + quad * 4;
    if (MODE == 0) {
      int b = row >> 10;
      int t = row & 1023;
#pragma unroll
      for (int ni = 0; ni < 4; ni++) {
        int col = bn * 128 + wn + ni * 16 + l16;
        int which = col / 768;        // wave-uniform per fragment (16 | 768)
        int cc = col - which * 768;
        int h = cc / 96;
        int d = cc - h * 96;
        if (which == 2) {
          // V^T layout: [bh][d][t]; r increments t -> 4 contiguous bf16 = one 8B store
          int base = ((2 * 64 + b * 8 + h) * 96 + d) * 1024 + t;
          union { unsigned short s[4]; uint2 u; } o;
#pragma unroll
          for (int r = 0; r < 4; r++) o.s[r] = f2bf(acc[mi][ni][r]);
          *(uint2*)(obf + base) = o.u;
        } else {
          int base = ((which * 64 + b * 8 + h) * 1024 + t) * 96 + d;
#pragma unroll
          for (int r = 0; r < 4; r++) obf[base + r * 96] = f2bf(acc[mi][ni][r]);
        }
      }
    } else {
#pragma unroll
      for (int ni = 0; ni < 4; ni++) {
        int col = bn * 128 + wn + ni * 16 + l16;
#pragma unroll
        for (int r = 0; r < 4; r++) of32[(row + r) * 768 + col] = acc[mi][ni][r];
      }
    }
  }
}

// ---- flash attention: 1 block = (b,h) x 64 q-rows; 4 waves x 16 rows; BS=128 ----
// 16 q-rows/wave, grid 64x16 = 1024 blocks, LDS 43.5KB -> 3 blocks/CU (12 waves/CU).
// Tile j = 15-by: heavy tiles dispatch first, CU classes get balanced iteration sets.
__global__ __launch_bounds__(256, 3)
void attn(const unsigned short* __restrict__ qkv, unsigned short* __restrict__ y) {
  const int bh = blockIdx.x;
  const int by = blockIdx.y;
  const int q0 = (15 - by) * 64;           // heavy tiles dispatch first, class-balanced
  const int tid = threadIdx.x;
  const int wave = tid >> 6, lane = tid & 63;
  const int quad = lane >> 4, l16 = lane & 15;
  const int qw0 = q0 + wave * 16;          // this wave's 16 q-rows (1 m-tile)
  const int b = bh >> 3, h = bh & 7;

  const unsigned short* Qh = qkv + bh * Tz * Dz;
  const unsigned short* Kh = qkv + (BHz + bh) * Tz * Dz;
  const unsigned short* Vt = qkv + 2 * BHz * Tz * Dz + bh * Dz * Tz;  // V^T [d][t]

  __shared__ unsigned short Vsm[96 * 136];       // V^T [d][s], stride 136 (26112 B)
  __shared__ unsigned short Psm[4 * 16 * 136];   // per-wave P [16 q][128 s] (17408 B)
  unsigned short* Pw = Psm + wave * 16 * 136;

  // V staging thread map: round g covers rows g*16 + (tid>>4), 16B chunk tid&15
  const int vd = tid >> 4;
  const int vc = tid & 15;

  bf16x8 aq[3];
#pragma unroll
  for (int kd = 0; kd < 3; kd++)
    aq[kd] = *(const bf16x8*)(Qh + (qw0 + l16) * Dz + kd * 32 + quad * 8);

  f32x4 zero = {0.f, 0.f, 0.f, 0.f};
  f32x4 acc_o[6];
#pragma unroll
  for (int i = 0; i < 6; i++) acc_o[i] = zero;
  const float NEG = -__builtin_inff();
  float mrow[4], lrow[4];                  // mrow raw-score domain; lrow per-LANE partial
#pragma unroll
  for (int r = 0; r < 4; r++) { mrow[r] = NEG; lrow[r] = 0.f; }
  const float cs = 0.14724538519872735f;   // (1/sqrt(96)) * log2(e): exp2-domain softmax

  const int s_last = (q0 >> 7) << 7;       // floor(q0/128)*128
  for (int s0 = 0; s0 <= s_last; s0 += 128) {
    // ---- T14 issue-early: V^T tile global->reg; latency hides under QK^T+softmax ----
    u16x8 vreg[6];
#pragma unroll
    for (int g = 0; g < 6; g++)
      vreg[g] = *(const u16x8*)(Vt + (g * 16 + vd) * Tz + s0 + vc * 8);

    const int srem = qw0 + 15 - s0;              // >= 15 always; srem%16==15
    const int nlim = min(7, srem >> 4);          // last 16-wide s tile with unmasked cols
    const int klim = min(3, srem >> 5);          // last 32-wide PV k chunk

    // ---- S = Q K^T ----
    f32x4 sacc[8];
#pragma unroll
    for (int ni = 0; ni < 8; ni++) {
      if (ni <= nlim) {
        sacc[ni] = zero;
#pragma unroll
        for (int kd = 0; kd < 3; kd++) {
          bf16x8 bk = *(const bf16x8*)(Kh + (s0 + ni * 16 + l16) * Dz + kd * 32 + quad * 8);
          sacc[ni] = __builtin_amdgcn_mfma_f32_16x16x32_bf16(aq[kd], bk, sacc[ni], 0, 0, 0);
        }
      }
    }

    // ---- online softmax; P written to this wave's LDS region ----
    float rmax[4] = {NEG, NEG, NEG, NEG};
#pragma unroll
    for (int ni = 0; ni < 8; ni++) {
      if (ni <= nlim) {
        // mask only tiles that straddle/cross the diagonal (wave-uniform test)
        if (s0 + ni * 16 + 15 > qw0) {
          const int t_base = qw0 + quad * 4;
          const int s_abs = s0 + ni * 16 + l16;
#pragma unroll
          for (int r = 0; r < 4; r++)
            if (s_abs > t_base + r) sacc[ni][r] = NEG;
        }
#pragma unroll
        for (int r = 0; r < 4; r++) rmax[r] = fmaxf(rmax[r], sacc[ni][r]);
      }
    }
#pragma unroll
    for (int r = 0; r < 4; r++)
#pragma unroll
      for (int sh = 1; sh < 16; sh <<= 1)
        rmax[r] = fmaxf(rmax[r], __shfl_xor(rmax[r], sh));

    // deferred rescale (T13): only pay the alpha pass when max grew past threshold
    // 54 raw ~= 8 exp2-units -> p bounded by 2^8, fine in bf16/f32
    int ok = 1;
#pragma unroll
    for (int r = 0; r < 4; r++) ok &= (rmax[r] <= mrow[r] + 54.0f) ? 1 : 0;
    if (!__all(ok)) {
#pragma unroll
      for (int r = 0; r < 4; r++) {
        float mnew = fmaxf(mrow[r], rmax[r]);
        float alpha = EXP2((mrow[r] - mnew) * cs);   // m=-inf -> alpha=0 first iter
        mrow[r] = mnew;
        lrow[r] *= alpha;
#pragma unroll
        for (int di = 0; di < 6; di++) acc_o[di][r] *= alpha;
      }
    }

    float nmc[4];
#pragma unroll
    for (int r = 0; r < 4; r++) nmc[r] = -mrow[r] * cs;
    float rsum[4] = {0.f, 0.f, 0.f, 0.f};
#pragma unroll
    for (int ni = 0; ni < 8; ni++) {
      if (ni <= nlim) {
#pragma unroll
        for (int r = 0; r < 4; r++) {
          float p = EXP2(fmaf(sacc[ni][r], cs, nmc[r]));  // masked: exp2(-inf)=0
          rsum[r] += p;
          Pw[(quad * 4 + r) * 136 + ni * 16 + l16] = f2bf(p);
        }
      }
    }
#pragma unroll
    for (int r = 0; r < 4; r++) lrow[r] += rsum[r];   // per-lane partial; reduce at end

    // zero-fill: when nlim is even, PV chunk klim reads unwritten tile nlim+1
    if (nlim < 7 && !(nlim & 1)) {
      const int zc = (nlim + 1) * 16 + l16;
#pragma unroll
      for (int r = 0; r < 4; r++) Pw[(quad * 4 + r) * 136 + zc] = 0;
    }

    // ---- T14 write-late: V regs -> LDS after WAR barrier (vectorized b128) ----
    __syncthreads();                 // prior iter's Vsm reads done
#pragma unroll
    for (int g = 0; g < 6; g++)
      *(u16x8*)&Vsm[(g * 16 + vd) * 136 + vc * 8] = vreg[g];
    __syncthreads();                 // Vsm ready

    // ---- O += P V : P from own-wave LDS (lgkmcnt orders), V from Vsm ----
#pragma unroll
    for (int kc = 0; kc < 4; kc++) {
      if (kc <= klim) {
        bf16x8 ap = *(const bf16x8*)&Pw[l16 * 136 + kc * 32 + quad * 8];
#pragma unroll
        for (int di = 0; di < 6; di++) {
          bf16x8 bv = *(const bf16x8*)&Vsm[(di * 16 + l16) * 136 + kc * 32 + quad * 8];
          acc_o[di] = __builtin_amdgcn_mfma_f32_16x16x32_bf16(ap, bv, acc_o[di], 0, 0, 0);
        }
      }
    }
  }

#pragma unroll
  for (int r = 0; r < 4; r++) {
#pragma unroll
    for (int sh = 1; sh < 16; sh <<= 1)
      lrow[r] += __shfl_xor(lrow[r], sh);          // deferred l reduction
    float linv = 1.f / lrow[r];
    int t = qw0 + quad * 4 + r;
#pragma unroll
    for (int di = 0; di < 6; di++) {
      int d = di * 16 + l16;
      y[(b * Tz + t) * Cz + h * Dz + d] = f2bf(acc_o[di][r] * linv);
    }
  }
}

// ---- workspace layout (bytes) ----
#define OFF_XB   0u
#define OFF_WAT  12582912u            // 8192*768*2
#define OFF_WPT  16121856u            // + 2304*768*2
#define OFF_QKV  17301504u            // + 768*768*2
#define OFF_Y    55050240u            // + 3*64*1024*96*2

extern "C" void kernel_launch(void* const* d_in, const int* in_sizes, int n_in,
                              void* d_out, int out_size, void* d_ws, size_t ws_size,
                              hipStream_t stream) {
  const float* x  = (const float*)d_in[0];
  const float* Wa = (const float*)d_in[1];
  const float* Wp = (const float*)d_in[2];
  float* out = (float*)d_out;
  uint8_t* ws = (uint8_t*)d_ws;
  unsigned short* xb  = (unsigned short*)(ws + OFF_XB);
  unsigned short* Wat = (unsigned short*)(ws + OFF_WAT);
  unsigned short* Wpt = (unsigned short*)(ws + OFF_WPT);
  unsigned short* qkv = (unsigned short*)(ws + OFF_QKV);
  unsigned short* y   = (unsigned short*)(ws + OFF_Y);

  cast_f32_bf16<<<6144, 256, 0, stream>>>(x, xb);
  transpose_cast<<<dim3(36, 12), 256, 0, stream>>>(Wa, Wat, 768, 2304);
  transpose_cast<<<dim3(12, 12), 256, 0, stream>>>(Wp, Wpt, 768, 768);
  gemm128<0><<<dim3(64, 18), 256, 0, stream>>>(xb, Wat, qkv, nullptr);
  attn<<<dim3(64, 16), 256, 0, stream>>>(qkv, y);
  gemm128<1><<<dim3(64, 6), 256, 0, stream>>>(y, Wpt, nullptr, out);
}